// Round 2
// baseline (99.783 us; speedup 1.0000x reference)
//
#include <hip/hip_runtime.h>
#include <hip/hip_bf16.h>
#include <stdint.h>

// Masked scaled-dot attention, B=2 H=16 S=2048 D=64, fp32 in/out.
// Flash-style, bf16 MFMA 32x32x16, swapped QK^T (S[k][q]) and swapped PV
// (O^T[d][q]) so softmax stats and rescale are lane-local. PV uses a
// split-half (hi,j)->k map on BOTH operands => correct for any hw k-map,
// no cross-lane P exchange needed. Mask via k-major ballot bitmask in ws.

#define SLEN 2048
#define DK 64
#define KVB 64
#define NT (SLEN / KVB)   // 32 KV tiles
#define QTILE 256         // 8 waves * 32 q-rows

typedef __attribute__((ext_vector_type(8)))  short    short8;
typedef __attribute__((ext_vector_type(4)))  short    s4v;
typedef __attribute__((ext_vector_type(16))) float    f32x16;
typedef __attribute__((ext_vector_type(4)))  float    float4v;
typedef __attribute__((ext_vector_type(4)))  unsigned uint4v;
typedef __attribute__((ext_vector_type(4)))  int      int4v;

static __device__ __forceinline__ float fexp2(float x){
#if __has_builtin(__builtin_amdgcn_exp2f)
  return __builtin_amdgcn_exp2f(x);
#else
  float r; asm("v_exp_f32 %0, %1" : "=v"(r) : "v"(x)); return r;
#endif
}
static __device__ __forceinline__ unsigned short f2bfu(float x){
  __hip_bfloat16 h = __float2bfloat16(x);
  return __builtin_bit_cast(unsigned short, h);
}
static __device__ __forceinline__ unsigned pkbf(float lo, float hi){
  return (unsigned)f2bfu(lo) | ((unsigned)f2bfu(hi) << 16);
}
static __device__ __forceinline__ short8 pack8s(float4v a, float4v b, float s){
  short8 r;
  r[0]=(short)f2bfu(a[0]*s); r[1]=(short)f2bfu(a[1]*s);
  r[2]=(short)f2bfu(a[2]*s); r[3]=(short)f2bfu(a[3]*s);
  r[4]=(short)f2bfu(b[0]*s); r[5]=(short)f2bfu(b[1]*s);
  r[6]=(short)f2bfu(b[2]*s); r[7]=(short)f2bfu(b[3]*s);
  return r;
}

// k-major bitmask: word mtw[i*4096 + q*2 + h] bit b = (mask[q][i*64 + h*32 + b] != 0)
// (stored as one 64-bit ballot per (q, 64-k group))
__global__ void ScaledDotAttention_mask_pack(const int* __restrict__ mask,
                                             uint32_t* __restrict__ mtw){
  int lane = threadIdx.x & 63;
  int wid  = threadIdx.x >> 6;
  int q    = blockIdx.x * 4 + wid;
  const int* row = mask + (size_t)q * SLEN;
  #pragma unroll 4
  for (int i = 0; i < 32; ++i){
    unsigned long long b = __ballot(row[i*64 + lane] != 0);
    if (lane == 0)
      *(unsigned long long*)(mtw + (size_t)i*4096 + (size_t)q*2) = b;
  }
}

template<bool USE_WS>
__global__ __launch_bounds__(512, 2)
void ScaledDotAttention_attn(const float* __restrict__ Q, const float* __restrict__ K,
                             const float* __restrict__ V, const uint32_t* __restrict__ mtw,
                             const int* __restrict__ mask, float* __restrict__ Out)
{
  __shared__ alignas(16) unsigned short Kl[KVB*DK];  // [k][d] bf16, rows XOR-swz by (k&7)<<4
  __shared__ alignas(16) unsigned short Vt[DK*KVB];  // V^T [d][k] bf16, rows XOR-swz by (d&15)<<3

  const int tid  = threadIdx.x;
  const int lane = tid & 63;
  const int l31  = lane & 31;
  const int hi   = lane >> 5;
  const int wid  = __builtin_amdgcn_readfirstlane(tid >> 6);

  // XCD-aware mapping: the 8 q-tiles of one bh spread over blocks sharing an XCD's L2.
  const int bid = blockIdx.x;
  const int xcd = bid & 7, ii = bid >> 3;
  const int bh  = xcd + 8*(ii & 3);    // 0..31
  const int qt  = ii >> 2;             // 0..7

  const float* Qb = Q + (size_t)bh*SLEN*DK;
  const float* Kb = K + (size_t)bh*SLEN*DK;
  const float* Vb = V + (size_t)bh*SLEN*DK;

  const int qbase = qt*QTILE + wid*32;
  const float C1 = 0.18033688011112042592f;  // log2(e)/8, folded into Q

  // Q fragments (B-operand of QK): lane l31 = q, element j of chunk c -> d = c*16 + hi*8 + j
  short8 qf[4];
  {
    const float* qrow = Qb + (size_t)(qbase + l31)*DK + hi*8;
    #pragma unroll
    for (int c = 0; c < 4; ++c){
      float4v f0 = *(const float4v*)(qrow + c*16);
      float4v f1 = *(const float4v*)(qrow + c*16 + 4);
      qf[c] = pack8s(f0, f1, C1);
    }
  }

  f32x16 O0, O1;    // O^T accum: lane holds q=l31, d = (r&3)+8*(r>>2)+4*hi (+32 for O1)
  #pragma unroll
  for (int r = 0; r < 16; ++r){ O0[r] = 0.f; O1[r] = 0.f; }
  float m = -1.0e4f, lsum = 0.f;
  const float vneg = -1.0e9f;

  // staging: thread -> K/V row skr, 8-col chunk sc8b
  const int skr  = tid >> 3;
  const int sc8b = tid & 7;
  float4v ka0, ka1, va0, va1;

  auto LOADT = [&](int it){
    const float* kp = Kb + (size_t)it*KVB*DK + skr*DK + sc8b*8;
    ka0 = *(const float4v*)kp;  ka1 = *(const float4v*)(kp + 4);
    const float* vp = Vb + (size_t)it*KVB*DK + skr*DK + sc8b*8;
    va0 = *(const float4v*)vp;  va1 = *(const float4v*)(vp + 4);
  };

  LOADT(0);

  #pragma unroll 1
  for (int it = 0; it < NT; ++it){
    __syncthreads();
    {
      // K: row-major swizzled, one ds_write_b128
      short8 kw = pack8s(ka0, ka1, 1.0f);
      int kaddr = (skr*128 + sc8b*16) ^ ((skr & 7) << 4);
      *(short8*)((char*)Kl + kaddr) = kw;
      // V^T: scatter 8 b16 writes; element (d = sc8b*8+j, k = skr)
      unsigned short vs[8];
      vs[0]=f2bfu(va0[0]); vs[1]=f2bfu(va0[1]); vs[2]=f2bfu(va0[2]); vs[3]=f2bfu(va0[3]);
      vs[4]=f2bfu(va1[0]); vs[5]=f2bfu(va1[1]); vs[6]=f2bfu(va1[2]); vs[7]=f2bfu(va1[3]);
      #pragma unroll
      for (int j = 0; j < 8; ++j){
        int d = sc8b*8 + j;
        int vaddr = (d*128 + skr*2) ^ ((d & 15) << 3);
        *(unsigned short*)((char*)Vt + vaddr) = vs[j];
      }
    }
    __syncthreads();
    if (it + 1 < NT) LOADT(it + 1);   // overlaps with compute below

    uint64_t wv = 0;
    if constexpr (USE_WS){
      wv = *(const uint64_t*)(mtw + (size_t)it*4096 + (size_t)(qbase + l31)*2);
    }

    #pragma unroll
    for (int ks = 0; ks < 2; ++ks){
      // QK^T swapped: S[k][q].  A = K rows (lane l31 = k-row), B = Q.
      f32x16 acc;
      #pragma unroll
      for (int r = 0; r < 16; ++r) acc[r] = 0.f;
      #pragma unroll
      for (int dc = 0; dc < 4; ++dc){
        int kaddr = ((ks*32 + l31)*128 + dc*32 + hi*16) ^ ((l31 & 7) << 4);
        short8 kf = *(const short8*)((const char*)Kl + kaddr);
        acc = __builtin_amdgcn_mfma_f32_32x32x16_bf16(kf, qf[dc], acc, 0, 0, 0);
      }
      // masking: lane holds (q = l31, k = it*64 + ks*32 + (r&3)+8*(r>>2)+4*hi)
      float t[16];
      if constexpr (USE_WS){
        uint32_t w = (uint32_t)(wv >> (32*ks)) >> (4*hi);
        #pragma unroll
        for (int r = 0; r < 16; ++r){
          unsigned bit = (w >> ((r & 3) + 8*(r >> 2))) & 1u;
          t[r] = bit ? acc[r] : vneg;
        }
      } else {
        const int* mri = mask + (size_t)(qbase + l31)*SLEN + it*KVB + ks*32 + 4*hi;
        int4v g0 = *(const int4v*)(mri);
        int4v g1 = *(const int4v*)(mri + 8);
        int4v g2 = *(const int4v*)(mri + 16);
        int4v g3 = *(const int4v*)(mri + 24);
        #pragma unroll
        for (int r = 0; r < 16; ++r){
          int gi = r >> 2;
          int gv = (gi==0 ? g0[r&3] : gi==1 ? g1[r&3] : gi==2 ? g2[r&3] : g3[r&3]);
          t[r] = gv ? acc[r] : vneg;
        }
      }
      // tile max (tree), then partner-lane combine via shfl_xor (unambiguous)
      float mx[8];
      #pragma unroll
      for (int r = 0; r < 8; ++r) mx[r] = fmaxf(t[r], t[r+8]);
      float u0 = fmaxf(fmaxf(mx[0], mx[1]), mx[2]);
      float u1 = fmaxf(fmaxf(mx[3], mx[4]), mx[5]);
      float u2 = fmaxf(fmaxf(mx[6], mx[7]), u0);
      float mt = fmaxf(u1, u2);
      mt = fmaxf(mt, __shfl_xor(mt, 32, 64));
      // defer-max (T13, THR=8)
      if (!__all(mt <= m + 8.0f)){
        float mn = fmaxf(m, mt);
        float sc = fexp2(m - mn);
        m = mn;
        lsum *= sc;
        #pragma unroll
        for (int r = 0; r < 16; ++r){ O0[r] *= sc; O1[r] *= sc; }
      }
      float p[16];
      #pragma unroll
      for (int r = 0; r < 16; ++r) p[r] = fexp2(t[r] - m);
      float q0 = (p[0]+p[1]) + (p[2]+p[3]);
      float q1 = (p[4]+p[5]) + (p[6]+p[7]);
      float q2 = (p[8]+p[9]) + (p[10]+p[11]);
      float q3 = (p[12]+p[13]) + (p[14]+p[15]);
      lsum += (q0+q1) + (q2+q3);

      // PV swapped: O^T = V^T * P.  Both operands use the split-half map
      // (hi,j): j=0..3 -> k = base + 4*hi + j ; j=4..7 -> k = base + 8 + 4*hi + (j-4)
      // P already holds exactly these k's as p[8*kc + j]  => no lane exchange.
      #pragma unroll
      for (int kc = 0; kc < 2; ++kc){
        unsigned pw0 = pkbf(p[8*kc+0], p[8*kc+1]);
        unsigned pw1 = pkbf(p[8*kc+2], p[8*kc+3]);
        unsigned pw2 = pkbf(p[8*kc+4], p[8*kc+5]);
        unsigned pw3 = pkbf(p[8*kc+6], p[8*kc+7]);
        uint4v pw; pw[0]=pw0; pw[1]=pw1; pw[2]=pw2; pw[3]=pw3;
        short8 pf = __builtin_bit_cast(short8, pw);
        int kbyte = (ks*32 + kc*16 + 4*hi) * 2;   // byte offset of k within a Vt row
        #pragma unroll
        for (int hf = 0; hf < 2; ++hf){
          int d = hf*32 + l31;
          int rowb = d*128;
          int swz = (d & 15) << 3;
          s4v a = *(const s4v*)((const char*)Vt + ((rowb + kbyte) ^ swz));
          s4v b = *(const s4v*)((const char*)Vt + ((rowb + kbyte + 16) ^ swz));
          short8 vf;
          #pragma unroll
          for (int j = 0; j < 4; ++j){ vf[j] = a[j]; vf[4+j] = b[j]; }
          if (hf == 0) O0 = __builtin_amdgcn_mfma_f32_32x32x16_bf16(vf, pf, O0, 0, 0, 0);
          else         O1 = __builtin_amdgcn_mfma_f32_32x32x16_bf16(vf, pf, O1, 0, 0, 0);
        }
      }
    }
  }

  // epilogue: combine partner lsum, normalize, store (O^T: q=l31, d=(r&3)+8*(r>>2)+4hi)
  float lt = lsum + __shfl_xor(lsum, 32, 64);
  float rinv = 1.0f / lt;
  float* orow = Out + ((size_t)bh*SLEN + qbase + l31)*DK;
  #pragma unroll
  for (int r = 0; r < 16; ++r){
    int c0 = (r & 3) + 8*(r >> 2) + 4*hi;
    orow[c0]      = O0[r] * rinv;
    orow[c0 + 32] = O1[r] * rinv;
  }
}

extern "C" void kernel_launch(void* const* d_in, const int* in_sizes, int n_in,
                              void* d_out, int out_size, void* d_ws, size_t ws_size,
                              hipStream_t stream) {
  const float* Q    = (const float*)d_in[0];
  const float* K    = (const float*)d_in[1];
  const float* V    = (const float*)d_in[2];
  const int*   mask = (const int*)d_in[3];
  float* Out = (float*)d_out;

  if (ws_size >= (size_t)(SLEN/64) * SLEN * 2 * sizeof(uint32_t)) {   // 512 KiB
    uint32_t* mtw = (uint32_t*)d_ws;
    ScaledDotAttention_mask_pack<<<dim3(SLEN/4), dim3(256), 0, stream>>>(mask, mtw);
    ScaledDotAttention_attn<true><<<dim3(256), dim3(512), 0, stream>>>(Q, K, V, mtw, mask, Out);
  } else {
    ScaledDotAttention_attn<false><<<dim3(256), dim3(512), 0, stream>>>(Q, K, V, (const uint32_t*)nullptr, mask, Out);
  }
}